// Round 7
// baseline (155.070 us; speedup 1.0000x reference)
//
#include <hip/hip_runtime.h>
#include <stddef.h>

// ---------- types ----------
typedef __bf16 bf16x8 __attribute__((ext_vector_type(8)));
typedef __bf16 bf16x4 __attribute__((ext_vector_type(4)));
typedef float  f32x4  __attribute__((ext_vector_type(4)));

#define MFMA16(a, b, c) __builtin_amdgcn_mfma_f32_16x16x32_bf16((a), (b), (c), 0, 0, 0)

// async global->LDS, 16B per lane; LDS dest is wave-uniform base + lane*16
__device__ __forceinline__ void gload_lds16(const void* gsrc, void* ldst) {
    __builtin_amdgcn_global_load_lds(
        (__attribute__((address_space(1))) void*)gsrc,
        (__attribute__((address_space(3))) void*)ldst,
        16, 0, 0);
}

// ---------- K0: fused prep = fp32->bf16 cast of x  +  transpose+cast of both weights ----------
__global__ void prep_kernel(const float* __restrict__ x, __bf16* __restrict__ xbf,
                            const float* __restrict__ Wqkv, __bf16* __restrict__ WqkvT,
                            const float* __restrict__ Wproj, __bf16* __restrict__ WprojT) {
    __shared__ float tile[32][33];
    const int bx = blockIdx.x, tid = threadIdx.x;
    if (bx < 3072) {                       // cast x: 786432 float4 groups
        int i = bx * 256 + tid;
        float4 v = ((const float4*)x)[i];
        bf16x4 o = {(__bf16)v.x, (__bf16)v.y, (__bf16)v.z, (__bf16)v.w};
        ((bf16x4*)xbf)[i] = o;
        return;
    }
    const float* in; __bf16* out; int R, C, c0, r0;
    if (bx < 4800) { int bb = bx - 3072; in = Wqkv;  out = WqkvT;  R = 768; C = 2304;
                     c0 = (bb % 72) * 32; r0 = (bb / 72) * 32; }
    else           { int bb = bx - 4800; in = Wproj; out = WprojT; R = 768; C = 768;
                     c0 = (bb % 24) * 32; r0 = (bb / 24) * 32; }
    const int tx = tid & 31, ty = tid >> 5;    // 32 x 8
#pragma unroll
    for (int i = 0; i < 32; i += 8)
        tile[ty + i][tx] = in[(size_t)(r0 + ty + i) * C + c0 + tx];
    __syncthreads();
#pragma unroll
    for (int i = 0; i < 32; i += 8)
        out[(size_t)(c0 + ty + i) * R + r0 + tx] = (__bf16)tile[tx][ty + i];
}

// ---------- GEMM core: 128x128 tile, BK=64, 256 threads (4 waves, each 64x64) ----------
// LDS rows are 64 elems (8 chunks of 16B); chunk c of row r stored at slot c ^ (r&7).
__device__ __forceinline__ void gemm_core_bk64(
    const __bf16* __restrict__ A, const __bf16* __restrict__ Bt, int K,
    int m0, int n0, __bf16* aT, __bf16* bT, f32x4 acc[4][4]) {
    const int tid  = threadIdx.x;
    const int wid  = tid >> 6, lane = tid & 63;
    const int quad = lane >> 4, l16 = lane & 15;
    const int wm = (wid >> 1) * 64, wn = (wid & 1) * 64;
    const int r_in = lane >> 3;                    // 0..7
    const int cswz = ((lane & 7) ^ r_in) * 8;      // swizzled k-chunk offset (elems)
    const __bf16* gA = A  + (size_t)(m0 + wid * 8 + r_in) * K + cswz;
    const __bf16* gB = Bt + (size_t)(n0 + wid * 8 + r_in) * K + cswz;
    const int sA = (l16 & 7);
    for (int k0 = 0; k0 < K; k0 += 64) {
        __syncthreads();
#pragma unroll
        for (int j = 0; j < 4; j++) {
            gload_lds16(gA + (size_t)(j * 32) * K + k0, aT + (j * 32 + wid * 8) * 64);
            gload_lds16(gB + (size_t)(j * 32) * K + k0, bT + (j * 32 + wid * 8) * 64);
        }
        __syncthreads();
#pragma unroll
        for (int kh = 0; kh < 2; kh++) {
            bf16x8 af[4], bfr[4];
#pragma unroll
            for (int t = 0; t < 4; t++) {
                const int slot = ((kh * 4 + quad) ^ sA) << 3;
                af[t]  = *(const bf16x8*)(aT + (wm + t * 16 + l16) * 64 + slot);
                bfr[t] = *(const bf16x8*)(bT + (wn + t * 16 + l16) * 64 + slot);
            }
#pragma unroll
            for (int rt = 0; rt < 4; rt++)
#pragma unroll
                for (int ct = 0; ct < 4; ct++)
                    acc[rt][ct] = MFMA16(af[rt], bfr[ct], acc[rt][ct]);
        }
    }
}

// ---------- K1: QKV GEMM, epilogue scatters to q/k (bh,s,d) and vT (bh,d,s) ----------
__global__ __launch_bounds__(256, 3)
void gemm_qkv_kernel(const __bf16* __restrict__ A, const __bf16* __restrict__ Bt,
                     __bf16* __restrict__ qb, __bf16* __restrict__ kb,
                     __bf16* __restrict__ vtb) {
    __shared__ __bf16 aT[8192], bT[8192];
    f32x4 acc[4][4];
#pragma unroll
    for (int i = 0; i < 4; i++)
#pragma unroll
        for (int j = 0; j < 4; j++) { f32x4 z = {0.f, 0.f, 0.f, 0.f}; acc[i][j] = z; }
    const int m0 = blockIdx.x * 128, n0 = blockIdx.y * 128;
    gemm_core_bk64(A, Bt, 768, m0, n0, aT, bT, acc);
    const int tid = threadIdx.x, wid = tid >> 6, lane = tid & 63;
    const int quad = lane >> 4, l16 = lane & 15;
    const int wm = (wid >> 1) * 64, wn = (wid & 1) * 64;
#pragma unroll
    for (int rt = 0; rt < 4; rt++)
#pragma unroll
        for (int ct = 0; ct < 4; ct++) {
            const int ng = n0 + wn + ct * 16 + l16;
            const int which = ng / 768;
            const int rem = ng - which * 768;
            const int hh = rem >> 6, d = rem & 63;
#pragma unroll
            for (int r = 0; r < 4; r++) {
                const int mg = m0 + wm + rt * 16 + quad * 4 + r;
                const int b = mg >> 10, s = mg & 1023;
                const int bh = b * 12 + hh;
                __bf16 bv = (__bf16)acc[rt][ct][r];
                if (which == 0)      qb[((size_t)bh * 1024 + s) * 64 + d] = bv;
                else if (which == 1) kb[((size_t)bh * 1024 + s) * 64 + d] = bv;
                else                 vtb[((size_t)bh * 64 + d) * 1024 + s] = bv;
            }
        }
}

// ---------- K4: proj GEMM + bias, fp32 out ----------
__global__ __launch_bounds__(256, 3)
void gemm_proj_kernel(const __bf16* __restrict__ A, const __bf16* __restrict__ Bt,
                      const float* __restrict__ bias, float* __restrict__ out) {
    __shared__ __bf16 aT[8192], bT[8192];
    f32x4 acc[4][4];
#pragma unroll
    for (int i = 0; i < 4; i++)
#pragma unroll
        for (int j = 0; j < 4; j++) { f32x4 z = {0.f, 0.f, 0.f, 0.f}; acc[i][j] = z; }
    const int m0 = blockIdx.x * 128, n0 = blockIdx.y * 128;
    gemm_core_bk64(A, Bt, 768, m0, n0, aT, bT, acc);
    const int tid = threadIdx.x, wid = tid >> 6, lane = tid & 63;
    const int quad = lane >> 4, l16 = lane & 15;
    const int wm = (wid >> 1) * 64, wn = (wid & 1) * 64;
#pragma unroll
    for (int rt = 0; rt < 4; rt++)
#pragma unroll
        for (int ct = 0; ct < 4; ct++) {
            const int ng = n0 + wn + ct * 16 + l16;
            const float bb = bias[ng];
#pragma unroll
            for (int r = 0; r < 4; r++) {
                const int mg = m0 + wm + rt * 16 + quad * 4 + r;
                out[(size_t)mg * 768 + ng] = acc[rt][ct][r] + bb;
            }
        }
}

// ---------- K3: attention v5 — 4-wave blocks, Q-tile=64 (16 rows/wave), 3 waves/SIMD.
// grid (48 bh, 16 qt), block 256, LDS 50.4 KB -> 3 blocks/CU = 12 waves/CU.
// Wave wid owns tile rows [wid*16, wid*16+16); h = qt*2 + (wid>>1) is wave-uniform;
// w coordinate of a row = (wid&1)*16 + row_local.
// kv[buf]: K at [0..4096) as (key,d) swizzled, V at [4096..8192) as (d,key) swizzled.
// Phase A overlays kv[0] with Dw[wave][16r][64j] fp32 for the rel_w Toeplitz gather.
__global__ __launch_bounds__(256, 3)
void attn_kernel(const __bf16* __restrict__ q, const __bf16* __restrict__ kk,
                 const __bf16* __restrict__ vt, const float* __restrict__ rph,
                 const float* __restrict__ rpw, __bf16* __restrict__ aout) {
    __shared__ __bf16 kv[2][8192];
    __shared__ __bf16 pbuf[4][16 * 72];
    __shared__ float  relh[64][33];
    const int tid = threadIdx.x, wid = tid >> 6, lane = tid & 63;
    const int quad = lane >> 4, l16 = lane & 15;
    const int bh = blockIdx.x, qt = blockIdx.y;     // bh-major -> XCD-local q-tiles
    const int b = bh / 12, hh = bh - b * 12;
    const int q0 = qt * 64;
    const int w0 = wid * 16;               // wave's first row within the tile
    const int h = qt * 2 + (wid >> 1);     // wave-uniform h coordinate

    // q fragments (A-layout): rows q0 + w0 + l16
    const __bf16* qp = q + ((size_t)bh * 1024 + q0 + w0 + l16) * 64;
    bf16x8 aq0 = *(const bf16x8*)(qp + quad * 8);
    bf16x8 aq1 = *(const bf16x8*)(qp + 32 + quad * 8);

    // ---- Phase A: rel_w D-GEMM (Toeplitz) + rel_h GEMM, via MFMA ----
    float* Dw = ((float*)kv) + wid * 1024;      // 16 rows x 64 cols fp32, per wave (in kv[0])
#pragma unroll
    for (int ct = 0; ct < 4; ct++) {
        int j = ct * 16 + l16; if (j > 62) j = 62;   // table has 63 rows; j=63 unused
        const float* tb = rpw + (size_t)j * 64;
        float4 t0 = *(const float4*)(tb + quad * 8);
        float4 t1 = *(const float4*)(tb + quad * 8 + 4);
        float4 t2 = *(const float4*)(tb + 32 + quad * 8);
        float4 t3 = *(const float4*)(tb + 32 + quad * 8 + 4);
        bf16x8 b0 = {(__bf16)t0.x, (__bf16)t0.y, (__bf16)t0.z, (__bf16)t0.w,
                     (__bf16)t1.x, (__bf16)t1.y, (__bf16)t1.z, (__bf16)t1.w};
        bf16x8 b1 = {(__bf16)t2.x, (__bf16)t2.y, (__bf16)t2.z, (__bf16)t2.w,
                     (__bf16)t3.x, (__bf16)t3.y, (__bf16)t3.z, (__bf16)t3.w};
        f32x4 z = {0.f, 0.f, 0.f, 0.f};
        z = MFMA16(aq0, b0, z);
        z = MFMA16(aq1, b1, z);
#pragma unroll
        for (int i = 0; i < 4; i++)
            Dw[(quad * 4 + i) * 64 + ct * 16 + l16] = z[i];
    }
#pragma unroll
    for (int ct = 0; ct < 2; ct++) {
        const int tr = h - (ct * 16 + l16) + 31;     // in [0,62]
        const float* tb = rph + (size_t)tr * 64;
        float4 t0 = *(const float4*)(tb + quad * 8);
        float4 t1 = *(const float4*)(tb + quad * 8 + 4);
        float4 t2 = *(const float4*)(tb + 32 + quad * 8);
        float4 t3 = *(const float4*)(tb + 32 + quad * 8 + 4);
        bf16x8 b0 = {(__bf16)t0.x, (__bf16)t0.y, (__bf16)t0.z, (__bf16)t0.w,
                     (__bf16)t1.x, (__bf16)t1.y, (__bf16)t1.z, (__bf16)t1.w};
        bf16x8 b1 = {(__bf16)t2.x, (__bf16)t2.y, (__bf16)t2.z, (__bf16)t2.w,
                     (__bf16)t3.x, (__bf16)t3.y, (__bf16)t3.z, (__bf16)t3.w};
        f32x4 z = {0.f, 0.f, 0.f, 0.f};
        z = MFMA16(aq0, b0, z);
        z = MFMA16(aq1, b1, z);
#pragma unroll
        for (int i = 0; i < 4; i++)
            relh[w0 + quad * 4 + i][ct * 16 + l16] = z[i];
    }
    // gather rel_w biases (Dw is wave-private): row_local = quad*4+r, w = (wid&1)*16 + row_local
    float bw[2][4];
#pragma unroll
    for (int r = 0; r < 4; r++) {
        const int rl = quad * 4 + r;
        const int w = (wid & 1) * 16 + rl;
        bw[0][r] = Dw[rl * 64 + w - l16 + 31];
        bw[1][r] = Dw[rl * 64 + w + 15 - l16];
    }
    __syncthreads();   // gathers done before staging overwrites the kv overlay

    // ---- main flash loop, double-buffered ----
    float l_run[4];
    f32x4 o_acc[4];
#pragma unroll
    for (int r = 0; r < 4; r++) l_run[r] = 0.f;
#pragma unroll
    for (int t = 0; t < 4; t++) { f32x4 z = {0.f, 0.f, 0.f, 0.f}; o_acc[t] = z; }

    const __bf16* kg0 = kk + (size_t)bh * 65536;
    const __bf16* vg0 = vt + (size_t)bh * 65536;
    const int cbase = wid * 2;                         // 4 waves stage 2 chunks each
    const int srow = lane >> 3;
    const int scol = ((lane & 7) ^ srow) * 8;          // swizzled global chunk
    const int swz0 = ((quad ^ (l16 & 7)) << 3);
    const int swz1 = (((quad | 4) ^ (l16 & 7)) << 3);
    __bf16* pw = pbuf[wid];

    auto stage = [&](int buf, int kt) {
        const __bf16* kg = kg0 + kt * 4096;
        const __bf16* vg = vg0 + kt * 64;
        __bf16* kb_ = &kv[buf][0];
        __bf16* vb_ = &kv[buf][4096];
#pragma unroll
        for (int j = 0; j < 2; j++) {
            const int c = cbase + j;
            gload_lds16(kg + (c * 8 + srow) * 64 + scol, kb_ + c * 512);
            gload_lds16(vg + (size_t)(c * 8 + srow) * 1024 + scol, vb_ + c * 512);
        }
    };

    stage(0, 0);
    for (int kt = 0; kt < 16; kt++) {
        const int cur = kt & 1;
        __syncthreads();                 // drains cur's staging; syncs all waves
        if (kt < 15) stage(1 - cur, kt + 1);   // async prefetch overlaps compute
        const __bf16* kbuf = &kv[cur][0];
        const __bf16* vbuf = &kv[cur][4096];

        // K fragments
        bf16x8 bk[4][2];
#pragma unroll
        for (int ct = 0; ct < 4; ct++) {
            const int key = ct * 16 + l16;
            bk[ct][0] = *(const bf16x8*)(kbuf + key * 64 + swz0);
            bk[ct][1] = *(const bf16x8*)(kbuf + key * 64 + swz1);
        }

        f32x4 sacc[4];
#pragma unroll
        for (int ct = 0; ct < 4; ct++) {
            f32x4 z = {0.f, 0.f, 0.f, 0.f};
            z = MFMA16(aq0, bk[ct][0], z);
            z = MFMA16(aq1, bk[ct][1], z);
            sacc[ct] = z;
        }
        float bh0[4], bh1[4];
#pragma unroll
        for (int r = 0; r < 4; r++) {
            bh0[r] = relh[w0 + quad * 4 + r][kt * 2];
            bh1[r] = relh[w0 + quad * 4 + r][kt * 2 + 1];
        }
#pragma unroll
        for (int ct = 0; ct < 4; ct++)
#pragma unroll
            for (int r = 0; r < 4; r++) {
                float sv = fmaf(sacc[ct][r], 0.125f,
                                (ct < 2 ? bh0[r] : bh1[r]) + ((ct & 1) ? bw[1][r] : bw[0][r]));
                float p = __expf(sv);
                l_run[r] += p;
                pw[(quad * 4 + r) * 72 + ct * 16 + l16] = (__bf16)p;
            }

        bf16x8 ap0 = *(const bf16x8*)(pw + l16 * 72 + quad * 8);
        bf16x8 ap1 = *(const bf16x8*)(pw + l16 * 72 + 32 + quad * 8);
#pragma unroll
        for (int nt = 0; nt < 4; nt++) {
            const int d = nt * 16 + l16;
            bf16x8 bv0 = *(const bf16x8*)(vbuf + d * 64 + swz0);
            bf16x8 bv1 = *(const bf16x8*)(vbuf + d * 64 + swz1);
            o_acc[nt] = MFMA16(ap0, bv0, o_acc[nt]);
            o_acc[nt] = MFMA16(ap1, bv1, o_acc[nt]);
        }
    }

#pragma unroll
    for (int r = 0; r < 4; r++) {
        float s = l_run[r];
        s += __shfl_xor(s, 1);
        s += __shfl_xor(s, 2);
        s += __shfl_xor(s, 4);
        s += __shfl_xor(s, 8);
        l_run[r] = 1.f / s;
    }
    const int srow_o = q0 + w0 + quad * 4;
#pragma unroll
    for (int nt = 0; nt < 4; nt++)
#pragma unroll
        for (int r = 0; r < 4; r++) {
            float v = o_acc[nt][r] * l_run[r];
            aout[((size_t)b * 1024 + srow_o + r) * 768 + hh * 64 + nt * 16 + l16] = (__bf16)v;
        }
}

// ---------- launch ----------
extern "C" void kernel_launch(void* const* d_in, const int* in_sizes, int n_in,
                              void* d_out, int out_size, void* d_ws, size_t ws_size,
                              hipStream_t stream) {
    const float* x     = (const float*)d_in[0];
    const float* Wqkv  = (const float*)d_in[1];
    const float* Wproj = (const float*)d_in[2];
    const float* bproj = (const float*)d_in[3];
    const float* rph   = (const float*)d_in[4];
    const float* rpw   = (const float*)d_in[5];
    float* out = (float*)d_out;
    char* ws = (char*)d_ws;

    __bf16* xbf    = (__bf16*)(ws);                 // 4096*768*2   = 6291456
    __bf16* WqkvT  = (__bf16*)(ws + 6291456);       // 2304*768*2   = 3538944
    __bf16* WprojT = (__bf16*)(ws + 9830400);       // 768*768*2    = 1179648
    __bf16* qb     = (__bf16*)(ws + 11010048);      // 48*1024*64*2 = 6291456
    __bf16* kb     = (__bf16*)(ws + 17301504);      // 6291456
    __bf16* vtb    = (__bf16*)(ws + 23592960);      // 6291456
    __bf16* aob    = (__bf16*)(ws + 29884416);      // 4096*768*2   = 6291456
    // total 36175872 bytes

    prep_kernel<<<dim3(5376), dim3(256), 0, stream>>>(x, xbf, Wqkv, WqkvT, Wproj, WprojT);
    gemm_qkv_kernel<<<dim3(32, 18), dim3(256), 0, stream>>>(xbf, WqkvT, qb, kb, vtb);
    attn_kernel<<<dim3(48, 16), dim3(256), 0, stream>>>(qb, kb, vtb, rph, rpw, aob);
    gemm_proj_kernel<<<dim3(32, 6), dim3(256), 0, stream>>>(aob, WprojT, bproj, out);
}